// Round 10
// baseline (149.534 us; speedup 1.0000x reference)
//
#include <hip/hip_runtime.h>

// QNet forward, MI355X — R10: ZERO-barrier wave-private kernel, 16 waves/CU.
// B=65536 rows, obs=1129 (37 self + 39*28 others).
// 128 thr (2 waves) per block, 16 rows/wave, grid 2048 -> 8 blocks/CU (1 round).
//
// R9 post-mortem: warm==cold persists; everything <20% busy; per-iter block-wide
// barrier convoy (4-wave lockstep) is the remaining temperature-independent
// serializer. R10: B fragments move to REGISTERS (6 coalesced dwordx4/chunk,
// prefetched 1 chunk ahead, even/odd sets) -> no shared LDS buffer -> no
// barriers anywhere. A tiles + pass-2 windows: R9's coalesced swizzled-source
// glds16, wave-private tri-buffers, counted vmcnt (derived per phase):
//   pass1 steady: younger-than-A(c) = 2 iters x (6 B + 2 A) = 16 -> vmcnt(16)
//   pass2 steady: younger-than-W(w) = 2 iters x 2 glds      = 4  -> vmcnt(4)
// Swizzle (R9, verified): LDS[r][p] = global unit p^(r&7); read pos g^(r&7).
//
// Fragment maps (gfx950 16x16x32 bf16): A/B: row|col = lane&15, k = 8*(lane>>4)+i
//   C/D: col = lane&15, row = 4*(lane>>4) + reg
// Split-bf16: 3-term logits/self/head, 2-term others.
//
// d_ws: 120 units of 128 bf16x8 (64 hi + 64 lo), 2KB each.
//   W_al: c*3+t | W_self: 108+c*2+t | W_oth'(K=32, leading zero row): 112+t
//   W_ao: 114+t | W_emb: 116+t | W_out: 118+t

typedef __bf16 bf16x8 __attribute__((ext_vector_type(8)));
typedef float  f32x4  __attribute__((ext_vector_type(4)));

constexpr int OBS = 1129;

#define MFMA(a, b, c) __builtin_amdgcn_mfma_f32_16x16x32_bf16((a), (b), (c), 0, 0, 0)

__device__ __forceinline__ float4 ld4(const float* p) {
    float4 v;
    __builtin_memcpy(&v, p, 16);
    return v;
}

__device__ __forceinline__ void split8(const float* a, bf16x8& h, bf16x8& l) {
#pragma unroll
    for (int i = 0; i < 8; ++i) {
        __bf16 hb = (__bf16)a[i];
        h[i] = hb;
        l[i] = (__bf16)(a[i] - (float)hb);
    }
}

__device__ __forceinline__ f32x4 mm3(bf16x8 ah, bf16x8 al, bf16x8 bh, bf16x8 bl, f32x4 c) {
    c = MFMA(ah, bh, c);
    c = MFMA(ah, bl, c);
    c = MFMA(al, bh, c);
    return c;
}

__device__ __forceinline__ void glds16(const void* g, void* l) {
    __builtin_amdgcn_global_load_lds((const __attribute__((address_space(1))) void*)g,
                                     (__attribute__((address_space(3))) void*)l, 16, 0, 0);
}

// ---------------- prep: split weights into fragment order ----------------
__global__ void prep_weights(const float* __restrict__ W_al,
                             const float* __restrict__ W_self,
                             const float* __restrict__ W_oth,
                             const float* __restrict__ W_ao,
                             const float* __restrict__ W_emb,
                             const float* __restrict__ W_out,
                             bf16x8* __restrict__ ws)
{
    const int u = blockIdx.x;     // 120 units
    const int l = threadIdx.x;    // 64 lanes
    const int s = l >> 4, col = l & 15;
    const float* W; int K, N, ld, c, t, shift = 0;
    if (u < 108)      { c = u / 3;         t = u % 3;         W = W_al;   K = 1129; N = 40; ld = 40; }
    else if (u < 112) { c = (u - 108) / 2; t = (u - 108) & 1; W = W_self; K = 37;   N = 32; ld = 32; }
    else if (u < 114) { c = 0;             t = u - 112;       W = W_oth;  K = 28;   N = 32; ld = 32; shift = 1; }
    else if (u < 116) { c = 0;             t = u - 114;       W = W_ao;   K = 32;   N = 32; ld = 32; }
    else if (u < 118) { c = 0;             t = u - 116;       W = W_emb;  K = 32;   N = 32; ld = 32; }
    else              { c = 0;             t = u - 118;       W = W_out;  K = 32;   N = 21; ld = 21; }
    const int j = t * 16 + col;
    bf16x8 h, lo;
#pragma unroll
    for (int i = 0; i < 8; ++i) {
        int k = c * 32 + s * 8 + i;
        int kk = k - shift;
        float w = (kk >= 0 && kk < K && j < N) ? W[kk * ld + j] : 0.f;
        __bf16 hb = (__bf16)w;
        h[i]  = hb;
        lo[i] = (__bf16)(w - (float)hb);
    }
    ws[u * 128 + l]      = h;
    ws[u * 128 + 64 + l] = lo;
}

// ---------------- main kernel: 128 threads (2 waves), 32 rows ----------------
__global__ __launch_bounds__(128, 4)
void qnet_fwd(const float* __restrict__ obs,
              const float* __restrict__ b_al,
              const float* __restrict__ b_ao,
              const float* __restrict__ b_emb,
              const float* __restrict__ b_out,
              const bf16x8* __restrict__ wf,
              float* __restrict__ out)
{
    __shared__ __align__(16) char arena[2][6144];   // per-wave: 3 x 2KB tri-buffer
    __shared__ float sW[2][656];                    // per-wave att weights [16][41]

    const int t    = threadIdx.x;
    const int lane = t & 63;
    const int wv   = t >> 6;
    const int s    = lane >> 4;
    const int cq   = lane & 15;
    const int rowbase = blockIdx.x * 32 + wv * 16;
    const float* __restrict__ orow = obs + (size_t)(rowbase + cq) * OBS;
    float* __restrict__ sWw = sW[wv];
    char* const AW = arena[wv];

    const f32x4 zf = {0.f, 0.f, 0.f, 0.f};

    // coalesced staging bases (source-swizzled; R9-verified)
    const size_t aB0 = (size_t)(rowbase + (lane >> 3)) * OBS + 4 * ((lane & 7) ^ (lane >> 3));
    const size_t aB1 = aB0 + (size_t)8 * OBS;
    const unsigned rdA0 = (unsigned)(cq * 128 + (((2 * s)     ^ (cq & 7)) << 4));
    const unsigned rdA1 = (unsigned)(cq * 128 + (((2 * s + 1) ^ (cq & 7)) << 4));

#define STAGE_A(K, C)                                                             \
    do {                                                                          \
        char* _d = AW + (K) * 2048;                                               \
        glds16(obs + aB0 + (C) * 32, _d);                                         \
        glds16(obs + aB1 + (C) * 32, _d + 1024);                                  \
    } while (0)

#define LOADB(SET, C)                                                             \
    do {                                                                          \
        const bf16x8* _bu = wf + (size_t)(C) * 384;                               \
        SET[0] = _bu[lane];       SET[1] = _bu[64 + lane];                        \
        SET[2] = _bu[128 + lane]; SET[3] = _bu[192 + lane];                       \
        SET[4] = _bu[256 + lane]; SET[5] = _bu[320 + lane];                       \
    } while (0)

    // ================= pass 1: logits = obs @ W_al (barrier-free) =============
    f32x4 acc0 = zf, acc1 = zf, acc2 = zf;
    bf16x8 BA[6], BB[6];

#define P1_MATH(FA0, FA1, SET)                                                    \
    do {                                                                          \
        float _av[8] = {(FA0).x, (FA0).y, (FA0).z, (FA0).w,                       \
                        (FA1).x, (FA1).y, (FA1).z, (FA1).w};                      \
        bf16x8 _ah, _al; split8(_av, _ah, _al);                                   \
        __builtin_amdgcn_s_setprio(1);                                            \
        acc0 = mm3(_ah, _al, SET[0], SET[1], acc0);                               \
        acc1 = mm3(_ah, _al, SET[2], SET[3], acc1);                               \
        acc2 = mm3(_ah, _al, SET[4], SET[5], acc2);                               \
        __builtin_amdgcn_s_setprio(0);                                            \
    } while (0)

    // iter: wait A(c) -> read frags -> drain reads -> load B(c+1) -> stage A(c+3)
#define P1_ITER(C, VM, USESET, LOADSET, DOSTAGE)                                  \
    do {                                                                          \
        asm volatile("s_waitcnt vmcnt(" #VM ")" ::: "memory");                    \
        __builtin_amdgcn_sched_barrier(0);                                        \
        const char* _ab = AW + ((C) % 3) * 2048;                                  \
        float4 fa0 = *(const float4*)(_ab + rdA0);                                \
        float4 fa1 = *(const float4*)(_ab + rdA1);                                \
        asm volatile("s_waitcnt lgkmcnt(0)" ::: "memory");                        \
        __builtin_amdgcn_sched_barrier(0);                                        \
        LOADB(LOADSET, (C) + 1);                                                  \
        if (DOSTAGE) STAGE_A((C) % 3, (C) + 3);                                   \
        P1_MATH(fa0, fa1, USESET);                                                \
    } while (0)

    STAGE_A(0, 0); STAGE_A(1, 1); STAGE_A(2, 2);
    LOADB(BA, 0);

    P1_ITER(0, 10, BA, BB, true);          // younger-than-A(0) = A1,A2,B0 = 10
    P1_ITER(1, 16, BB, BA, true);
    for (int cc = 1; cc < 16; ++cc) {      // c = 2..31
        const int c = 2 * cc;
        P1_ITER(c,     16, BA, BB, true);
        P1_ITER(c + 1, 16, BB, BA, true);
    }
    P1_ITER(32, 16, BA, BB, false);
    P1_ITER(33, 14, BB, BA, false);
    P1_ITER(34, 12, BA, BB, false);
    {   // c = 35: masked A tail via VGPR loads; B(35) in BB
        asm volatile("s_waitcnt vmcnt(0)" ::: "memory");
        __builtin_amdgcn_sched_barrier(0);
        float av[8] = {0, 0, 0, 0, 0, 0, 0, 0};
        if (s == 0) {
            float4 p = ld4(orow + 1120), q = ld4(orow + 1124);
            av[0] = p.x; av[1] = p.y; av[2] = p.z; av[3] = p.w;
            av[4] = q.x; av[5] = q.y; av[6] = q.z; av[7] = q.w;
        } else if (s == 1) {
            av[0] = orow[1128];
        }
        float4 fa0 = {av[0], av[1], av[2], av[3]};
        float4 fa1 = {av[4], av[5], av[6], av[7]};
        P1_MATH(fa0, fa1, BB);
    }

    // ===== softmax over 40 cols (wave-private; C rows: row = 4s+j) =====
    {
        const float bal0 = b_al[cq];
        const float bal1 = b_al[16 + cq];
        const bool  v2m  = (cq < 8);
        const float bal2 = v2m ? b_al[32 + cq] : 0.f;
#pragma unroll
        for (int j = 0; j < 4; ++j) {
            float v0 = acc0[j] + bal0, v1 = acc1[j] + bal1, vv = acc2[j] + bal2;
            float m = fmaxf(fmaxf(v0, v1), v2m ? vv : -3.4e38f);
#pragma unroll
            for (int d = 1; d < 16; d <<= 1) m = fmaxf(m, __shfl_xor(m, d));
            float e0 = __expf(v0 - m), e1 = __expf(v1 - m);
            float e2 = v2m ? __expf(vv - m) : 0.f;
            float sm = e0 + e1 + e2;
#pragma unroll
            for (int d = 1; d < 16; d <<= 1) sm += __shfl_xor(sm, d);
            float inv = 1.f / sm;
            const int row = s * 4 + j;
            sWw[row * 41 + cq]      = e0 * inv;
            sWw[row * 41 + 16 + cq] = e1 * inv;
            if (v2m) sWw[row * 41 + 32 + cq] = e2 * inv;
        }
    }

    // ================= pass 2: encodings, weighted sum =================
    f32x4 at0 = zf, at1 = zf;
    {   // self encoding (no relu), 3-term, weight att_w[row][0]
        f32x4 e0 = zf, e1 = zf;
        {
            float4 p = ld4(orow + s * 8), q = ld4(orow + s * 8 + 4);
            float av[8] = {p.x, p.y, p.z, p.w, q.x, q.y, q.z, q.w};
            bf16x8 ah, al; split8(av, ah, al);
            const bf16x8* bu = wf + (size_t)108 * 128;
            e0 = mm3(ah, al, bu[lane],       bu[64 + lane],  e0);
            e1 = mm3(ah, al, bu[128 + lane], bu[192 + lane], e1);
        }
        {
            float av[8] = {0, 0, 0, 0, 0, 0, 0, 0};
            if (s == 0) {
                float4 p = ld4(orow + 32);
                av[0] = p.x; av[1] = p.y; av[2] = p.z; av[3] = p.w;
                av[4] = orow[36];
            }
            bf16x8 ah, al; split8(av, ah, al);
            const bf16x8* bu = wf + (size_t)110 * 128;
            e0 = mm3(ah, al, bu[lane],       bu[64 + lane],  e0);
            e1 = mm3(ah, al, bu[128 + lane], bu[192 + lane], e1);
        }
#pragma unroll
        for (int j = 0; j < 4; ++j) {
            float w0 = sWw[(s * 4 + j) * 41];
            at0[j] = w0 * e0[j];
            at1[j] = w0 * e1[j];
        }
    }

    // ---- other agents 0..37: 1-agent windows, wave-private tri-buffer ----
    asm volatile("s_waitcnt vmcnt(0)" ::: "memory");   // clean slate for counting

    const bf16x8* bo = wf + (size_t)112 * 128;
    const bf16x8 Boh0 = bo[lane],       Bol0 = bo[64 + lane];
    const bf16x8 Boh1 = bo[128 + lane], Bol1 = bo[192 + lane];

    // window n: [16 rows][32 floats] from col 36+28n (virtual k=0 = W' zero row)
    const size_t pB0 = (size_t)(rowbase + (lane >> 3)) * OBS + 36 + 4 * ((lane & 7) ^ (lane >> 3));
    const size_t pB1 = pB0 + (size_t)8 * OBS;

#define STAGE_W(K, N)                                                             \
    do {                                                                          \
        char* _d = AW + (K) * 2048;                                               \
        glds16(obs + pB0 + 28 * (N), _d);                                         \
        glds16(obs + pB1 + 28 * (N), _d + 1024);                                  \
    } while (0)

#define PROC_W(N, U0, U1)                                                         \
    do {                                                                          \
        bf16x8 _ah;                                                               \
        _ah[0] = (__bf16)(U0).x; _ah[1] = (__bf16)(U0).y;                         \
        _ah[2] = (__bf16)(U0).z; _ah[3] = (__bf16)(U0).w;                         \
        _ah[4] = (__bf16)(U1).x; _ah[5] = (__bf16)(U1).y;                         \
        _ah[6] = (__bf16)(U1).z; _ah[7] = (__bf16)(U1).w;                         \
        __builtin_amdgcn_s_setprio(1);                                            \
        f32x4 _e0 = MFMA(_ah, Boh0, zf); _e0 = MFMA(_ah, Bol0, _e0);              \
        f32x4 _e1 = MFMA(_ah, Boh1, zf); _e1 = MFMA(_ah, Bol1, _e1);              \
        __builtin_amdgcn_s_setprio(0);                                            \
        _Pragma("unroll")                                                         \
        for (int _j = 0; _j < 4; ++_j) {                                          \
            float _wn = sWw[(s * 4 + _j) * 41 + 1 + (N)];                         \
            at0[_j] += _wn * fmaxf(_e0[_j], 0.f);                                 \
            at1[_j] += _wn * fmaxf(_e1[_j], 0.f);                                 \
        }                                                                         \
    } while (0)

#define P2_ITER(W, VM, DOSTAGE)                                                   \
    do {                                                                          \
        asm volatile("s_waitcnt vmcnt(" #VM ")" ::: "memory");                    \
        __builtin_amdgcn_sched_barrier(0);                                        \
        const char* _ab = AW + ((W) % 3) * 2048;                                  \
        float4 u00 = *(const float4*)(_ab + rdA0);                                \
        float4 u01 = *(const float4*)(_ab + rdA1);                                \
        asm volatile("s_waitcnt lgkmcnt(0)" ::: "memory");                        \
        __builtin_amdgcn_sched_barrier(0);                                        \
        if (DOSTAGE) STAGE_W((W) % 3, (W) + 3);                                   \
        PROC_W(W, u00, u01);                                                      \
    } while (0)

    STAGE_W(0, 0); STAGE_W(1, 1); STAGE_W(2, 2);

    for (int w = 0; w < 35; ++w)
        P2_ITER(w, 4, true);
    P2_ITER(35, 4, false);
    P2_ITER(36, 2, false);
    P2_ITER(37, 0, false);

    {   // agent 38 via VGPR loads (avoids OOB read past obs end)
        const float* op = orow + 1100;        // col 36 + 28*38
        float av[8];
        if (s < 3) {
            float4 p = ld4(op + s * 8), q = ld4(op + s * 8 + 4);
            av[0] = p.x; av[1] = p.y; av[2] = p.z; av[3] = p.w;
            av[4] = q.x; av[5] = q.y; av[6] = q.z; av[7] = q.w;
        } else {
            float4 p = ld4(op + 24);
            av[0] = p.x; av[1] = p.y; av[2] = p.z; av[3] = p.w;
            av[4] = op[28];
            av[5] = 0.f; av[6] = 0.f; av[7] = 0.f;
        }
        float4 u0 = {av[0], av[1], av[2], av[3]};
        float4 u1 = {av[4], av[5], av[6], av[7]};
        PROC_W(38, u0, u1);
    }

    // ============ head: 3 dense layers, wave-private LDS (AW reuse) ============
    __bf16* hiw = (__bf16*)AW;
    __bf16* low = hiw + 640;
    f32x4 x0 = at0, x1 = at1;
#pragma unroll
    for (int L = 0; L < 3; ++L) {
        const int unit = 114 + L * 2;
        const float* bias = (L == 0) ? b_ao : (L == 1) ? b_emb : b_out;
        const int N = (L == 2) ? 21 : 32;
#pragma unroll
        for (int j = 0; j < 4; ++j) {
            const int row = s * 4 + j;
            __bf16 h0 = (__bf16)x0[j];
            hiw[row * 40 + cq] = h0;
            low[row * 40 + cq] = (__bf16)(x0[j] - (float)h0);
            __bf16 h1 = (__bf16)x1[j];
            hiw[row * 40 + 16 + cq] = h1;
            low[row * 40 + 16 + cq] = (__bf16)(x1[j] - (float)h1);
        }
        bf16x8 ah = *(const bf16x8*)&hiw[cq * 40 + s * 8];
        bf16x8 al = *(const bf16x8*)&low[cq * 40 + s * 8];
        const bf16x8* bu = wf + (size_t)unit * 128;
        f32x4 y0 = mm3(ah, al, bu[lane],       bu[64 + lane],  zf);
        f32x4 y1 = mm3(ah, al, bu[128 + lane], bu[192 + lane], zf);
        const float bc0 = bias[cq];
        const float bc1 = (16 + cq < N) ? bias[16 + cq] : 0.f;
#pragma unroll
        for (int j = 0; j < 4; ++j) {
            y0[j] += bc0;
            y1[j] += bc1;
            if (L < 2) { y0[j] = fmaxf(y0[j], 0.f); y1[j] = fmaxf(y1[j], 0.f); }
        }
        x0 = y0; x1 = y1;
    }

#pragma unroll
    for (int j = 0; j < 4; ++j) {
        const int row = rowbase + s * 4 + j;
        out[(size_t)row * 21 + cq] = x0[j];
        if (cq < 5) out[(size_t)row * 21 + 16 + cq] = x1[j];
    }
}

extern "C" void kernel_launch(void* const* d_in, const int* in_sizes, int n_in,
                              void* d_out, int out_size, void* d_ws, size_t ws_size,
                              hipStream_t stream) {
    const float* obs    = (const float*)d_in[0];
    const float* W_al   = (const float*)d_in[1];
    const float* b_al   = (const float*)d_in[2];
    const float* W_self = (const float*)d_in[3];
    const float* W_oth  = (const float*)d_in[5];
    const float* W_ao   = (const float*)d_in[7];
    const float* b_ao   = (const float*)d_in[8];
    const float* W_emb  = (const float*)d_in[9];
    const float* b_emb  = (const float*)d_in[10];
    const float* W_out  = (const float*)d_in[11];
    const float* b_out  = (const float*)d_in[12];
    float* out = (float*)d_out;
    bf16x8* ws = (bf16x8*)d_ws;

    prep_weights<<<120, 64, 0, stream>>>(W_al, W_self, W_oth, W_ao, W_emb, W_out, ws);

    const int B = in_sizes[0] / OBS;        // 65536
    qnet_fwd<<<B / 32, 128, 0, stream>>>(obs, b_al, b_ao, b_emb, b_out,
                                         (const bf16x8*)ws, out);
}

// Round 12
// 121.001 us; speedup vs baseline: 1.2358x; 1.2358x over previous
//
#include <hip/hip_runtime.h>

// QNet forward, MI355X — R12: R11 with the att-weight index map FIXED.
// (R11 bug: weight for agent n is att_w[row][1+n]; R11 shuffled col n.)
// B=65536 rows, obs=1129 (37 self + 39*28 others).
// 256 thr (4 waves), 128 rows/block (32/wave), grid 512 -> 2 blocks/CU,
// 256 rows in flight per CU (2x R9). LDS 72KB: A tri 48K + B quad 24.5K.
//
// Att weights: NO LDS table — softmax normalizes accumulator registers in
// place; pass 2 fetches w[row][1+n] via __shfl from owner lane
// grp|((1+n)&15), register class (acc0/1/2) = (1+n)>>4, chosen per sub-loop
// (compile-time -> no dynamic reg indexing). Self: owner grp|0, class 0.
//
// Staging (R9-verified swizzle): LDS[r][p] = global unit p^(r&7), read pos
// g^(r&7); glds16 reads 8 rows x 16B coalesced. Counted vmcnt ledger:
//   pass1 steady: stage=6 ops/chunk, lookahead 2 -> vmcnt(12)
//   pass2 steady: stage=4 ops/window, lookahead 2 -> vmcnt(8)
//
// Fragment maps (gfx950 16x16x32 bf16): A/B: row|col = lane&15, k = 8*(lane>>4)+i
//   C/D: col = lane&15, row = 4*(lane>>4) + reg
// Split-bf16: 3-term logits/self/head, 2-term others.
//
// d_ws: 120 units of 128 bf16x8 (64 hi + 64 lo), 2KB each.
//   W_al: c*3+t | W_self: 108+c*2+t | W_oth'(K=32, leading zero row): 112+t
//   W_ao: 114+t | W_emb: 116+t | W_out: 118+t

typedef __bf16 bf16x8 __attribute__((ext_vector_type(8)));
typedef float  f32x4  __attribute__((ext_vector_type(4)));

constexpr int OBS = 1129;

#define MFMA(a, b, c) __builtin_amdgcn_mfma_f32_16x16x32_bf16((a), (b), (c), 0, 0, 0)

__device__ __forceinline__ float4 ld4(const float* p) {
    float4 v;
    __builtin_memcpy(&v, p, 16);
    return v;
}

__device__ __forceinline__ void split8(const float* a, bf16x8& h, bf16x8& l) {
#pragma unroll
    for (int i = 0; i < 8; ++i) {
        __bf16 hb = (__bf16)a[i];
        h[i] = hb;
        l[i] = (__bf16)(a[i] - (float)hb);
    }
}

__device__ __forceinline__ f32x4 mm3(bf16x8 ah, bf16x8 al, bf16x8 bh, bf16x8 bl, f32x4 c) {
    c = MFMA(ah, bh, c);
    c = MFMA(ah, bl, c);
    c = MFMA(al, bh, c);
    return c;
}

__device__ __forceinline__ void glds16(const void* g, void* l) {
    __builtin_amdgcn_global_load_lds((const __attribute__((address_space(1))) void*)g,
                                     (__attribute__((address_space(3))) void*)l, 16, 0, 0);
}

// ---------------- prep: split weights into fragment order ----------------
__global__ void prep_weights(const float* __restrict__ W_al,
                             const float* __restrict__ W_self,
                             const float* __restrict__ W_oth,
                             const float* __restrict__ W_ao,
                             const float* __restrict__ W_emb,
                             const float* __restrict__ W_out,
                             bf16x8* __restrict__ ws)
{
    const int u = blockIdx.x;     // 120 units
    const int l = threadIdx.x;    // 64 lanes
    const int s = l >> 4, col = l & 15;
    const float* W; int K, N, ld, c, t, shift = 0;
    if (u < 108)      { c = u / 3;         t = u % 3;         W = W_al;   K = 1129; N = 40; ld = 40; }
    else if (u < 112) { c = (u - 108) / 2; t = (u - 108) & 1; W = W_self; K = 37;   N = 32; ld = 32; }
    else if (u < 114) { c = 0;             t = u - 112;       W = W_oth;  K = 28;   N = 32; ld = 32; shift = 1; }
    else if (u < 116) { c = 0;             t = u - 114;       W = W_ao;   K = 32;   N = 32; ld = 32; }
    else if (u < 118) { c = 0;             t = u - 116;       W = W_emb;  K = 32;   N = 32; ld = 32; }
    else              { c = 0;             t = u - 118;       W = W_out;  K = 32;   N = 21; ld = 21; }
    const int j = t * 16 + col;
    bf16x8 h, lo;
#pragma unroll
    for (int i = 0; i < 8; ++i) {
        int k = c * 32 + s * 8 + i;
        int kk = k - shift;
        float w = (kk >= 0 && kk < K && j < N) ? W[kk * ld + j] : 0.f;
        __bf16 hb = (__bf16)w;
        h[i]  = hb;
        lo[i] = (__bf16)(w - (float)hb);
    }
    ws[u * 128 + l]      = h;
    ws[u * 128 + 64 + l] = lo;
}

// ---------------- main kernel: 256 threads (4 waves), 128 rows ----------------
__global__ __launch_bounds__(256, 2)
void qnet_fwd(const float* __restrict__ obs,
              const float* __restrict__ b_al,
              const float* __restrict__ b_ao,
              const float* __restrict__ b_emb,
              const float* __restrict__ b_out,
              const bf16x8* __restrict__ wf,
              float* __restrict__ out)
{
    // A region: wave wv at wv*12288, tri-buf k*4096 (rowset0 [0,2K), rowset1 [2K,4K))
    // B region: quad-buf at 49152 + k*6144
    __shared__ __align__(16) char arena[73728];

    const int t    = threadIdx.x;
    const int lane = t & 63;
    const int wv   = t >> 6;
    const int s    = lane >> 4;
    const int cq   = lane & 15;
    const int rowbase = blockIdx.x * 128 + wv * 32;
    const float* __restrict__ orow0 = obs + (size_t)(rowbase + cq) * OBS;
    const float* __restrict__ orow1 = orow0 + (size_t)16 * OBS;
    const char* __restrict__ wfb = (const char*)wf;
    char* const AW = arena + wv * 12288;
    char* const Bb = arena + 49152;

    const f32x4 zf = {0.f, 0.f, 0.f, 0.f};

    // coalesced staging bases (source-swizzled): glds i covers rows 8i..8i+7
    const size_t aB0 = (size_t)(rowbase + (lane >> 3)) * OBS + 4 * ((lane & 7) ^ (lane >> 3));
    const size_t aB1 = aB0 + (size_t)8 * OBS;
    const size_t aB2 = aB0 + (size_t)16 * OBS;
    const size_t aB3 = aB0 + (size_t)24 * OBS;
    const unsigned rdA0 = (unsigned)(cq * 128 + (((2 * s)     ^ (cq & 7)) << 4));
    const unsigned rdA1 = (unsigned)(cq * 128 + (((2 * s + 1) ^ (cq & 7)) << 4));

#define STAGE_A(K, C)                                                             \
    do {                                                                          \
        char* _d = AW + (K) * 4096;                                               \
        glds16(obs + aB0 + (C) * 32, _d);                                         \
        glds16(obs + aB1 + (C) * 32, _d + 1024);                                  \
        glds16(obs + aB2 + (C) * 32, _d + 2048);                                  \
        glds16(obs + aB3 + (C) * 32, _d + 3072);                                  \
    } while (0)
#define STAGE_B(K, C)                                                             \
    do {                                                                          \
        const char* _bs = wfb + (size_t)(C) * 6144;                               \
        char* _d = Bb + (K) * 6144;                                               \
        glds16(_bs + wv * 1024 + lane * 16, _d + wv * 1024);                      \
        glds16(_bs + (4 + (wv & 1)) * 1024 + lane * 16, _d + (4 + (wv & 1)) * 1024); \
    } while (0)

    // ================= pass 1: logits = obs @ W_al =================
    f32x4 a0_0 = zf, a0_1 = zf, a0_2 = zf;    // rowset 0, col-tiles 0..2
    f32x4 a1_0 = zf, a1_1 = zf, a1_2 = zf;    // rowset 1

#define P1_MATH(F00, F01, F10, F11, BP)                                           \
    do {                                                                          \
        float _v0[8] = {(F00).x, (F00).y, (F00).z, (F00).w,                       \
                        (F01).x, (F01).y, (F01).z, (F01).w};                      \
        float _v1[8] = {(F10).x, (F10).y, (F10).z, (F10).w,                       \
                        (F11).x, (F11).y, (F11).z, (F11).w};                      \
        bf16x8 _h0, _l0, _h1, _l1;                                                \
        split8(_v0, _h0, _l0);                                                    \
        split8(_v1, _h1, _l1);                                                    \
        const char* _bp = (const char*)(BP);                                      \
        bf16x8 b0h = *(const bf16x8*)(_bp + lane * 16);                           \
        bf16x8 b0l = *(const bf16x8*)(_bp + 1024 + lane * 16);                    \
        bf16x8 b1h = *(const bf16x8*)(_bp + 2048 + lane * 16);                    \
        bf16x8 b1l = *(const bf16x8*)(_bp + 3072 + lane * 16);                    \
        bf16x8 b2h = *(const bf16x8*)(_bp + 4096 + lane * 16);                    \
        bf16x8 b2l = *(const bf16x8*)(_bp + 5120 + lane * 16);                    \
        __builtin_amdgcn_s_setprio(1);                                            \
        a0_0 = mm3(_h0, _l0, b0h, b0l, a0_0);                                     \
        a0_1 = mm3(_h0, _l0, b1h, b1l, a0_1);                                     \
        a0_2 = mm3(_h0, _l0, b2h, b2l, a0_2);                                     \
        a1_0 = mm3(_h1, _l1, b0h, b0l, a1_0);                                     \
        a1_1 = mm3(_h1, _l1, b1h, b1l, a1_1);                                     \
        a1_2 = mm3(_h1, _l1, b2h, b2l, a1_2);                                     \
        __builtin_amdgcn_s_setprio(0);                                            \
    } while (0)

#define P1_ITER(C, VM, STA, STB)                                                  \
    do {                                                                          \
        asm volatile("s_waitcnt vmcnt(" #VM ")" ::: "memory");                    \
        __builtin_amdgcn_s_barrier();                                             \
        __builtin_amdgcn_sched_barrier(0);                                        \
        const char* _ab = AW + ((C) % 3) * 4096;                                  \
        float4 f00 = *(const float4*)(_ab + rdA0);                                \
        float4 f01 = *(const float4*)(_ab + rdA1);                                \
        float4 f10 = *(const float4*)(_ab + 2048 + rdA0);                         \
        float4 f11 = *(const float4*)(_ab + 2048 + rdA1);                         \
        asm volatile("s_waitcnt lgkmcnt(0)" ::: "memory");                        \
        __builtin_amdgcn_sched_barrier(0);                                        \
        if (STA) STAGE_A((C) % 3, (C) + 3);                                       \
        if (STB) STAGE_B(((C) + 3) & 3, (C) + 3);                                 \
        P1_MATH(f00, f01, f10, f11, Bb + ((C) & 3) * 6144);                       \
    } while (0)

    // prologue: stage chunks 0,1,2 (A tri bufs 0..2, B quad bufs 0..2)
    STAGE_A(0, 0); STAGE_B(0, 0);
    STAGE_A(1, 1); STAGE_B(1, 1);
    STAGE_A(2, 2); STAGE_B(2, 2);

    for (int c = 0; c < 32; ++c)
        P1_ITER(c, 12, true, true);
    P1_ITER(32, 12, false, true);      // stage B(35) only
    P1_ITER(33, 8,  false, false);
    P1_ITER(34, 2,  false, false);
    {   // c = 35: masked A tail via VGPR loads; B(35) in Bb buf 3
        asm volatile("s_waitcnt vmcnt(0)" ::: "memory");
        __builtin_amdgcn_s_barrier();
        __builtin_amdgcn_sched_barrier(0);
        float v0[8] = {0, 0, 0, 0, 0, 0, 0, 0};
        float v1[8] = {0, 0, 0, 0, 0, 0, 0, 0};
        if (s == 0) {
            float4 p = ld4(orow0 + 1120), q = ld4(orow0 + 1124);
            v0[0] = p.x; v0[1] = p.y; v0[2] = p.z; v0[3] = p.w;
            v0[4] = q.x; v0[5] = q.y; v0[6] = q.z; v0[7] = q.w;
            float4 r = ld4(orow1 + 1120), u = ld4(orow1 + 1124);
            v1[0] = r.x; v1[1] = r.y; v1[2] = r.z; v1[3] = r.w;
            v1[4] = u.x; v1[5] = u.y; v1[6] = u.z; v1[7] = u.w;
        } else if (s == 1) {
            v0[0] = orow0[1128];
            v1[0] = orow1[1128];
        }
        float4 f00 = {v0[0], v0[1], v0[2], v0[3]};
        float4 f01 = {v0[4], v0[5], v0[6], v0[7]};
        float4 f10 = {v1[0], v1[1], v1[2], v1[3]};
        float4 f11 = {v1[4], v1[5], v1[6], v1[7]};
        P1_MATH(f00, f01, f10, f11, Bb + 3 * 6144);
    }

    // ===== softmax: normalize IN REGISTERS (att weights stay in accs) =====
    {
        const float bal0 = b_al[cq];
        const float bal1 = b_al[16 + cq];
        const bool  v2m  = (cq < 8);
        const float bal2 = v2m ? b_al[32 + cq] : 0.f;

#define SOFTMAX_RS(A0, A1, A2)                                                    \
    do {                                                                          \
        _Pragma("unroll")                                                         \
        for (int _j = 0; _j < 4; ++_j) {                                          \
            float v0 = A0[_j] + bal0, v1 = A1[_j] + bal1, vv = A2[_j] + bal2;     \
            float m = fmaxf(fmaxf(v0, v1), v2m ? vv : -3.4e38f);                  \
            _Pragma("unroll")                                                     \
            for (int d = 1; d < 16; d <<= 1) m = fmaxf(m, __shfl_xor(m, d));      \
            float e0 = __expf(v0 - m), e1 = __expf(v1 - m);                       \
            float e2 = v2m ? __expf(vv - m) : 0.f;                                \
            float sm = e0 + e1 + e2;                                              \
            _Pragma("unroll")                                                     \
            for (int d = 1; d < 16; d <<= 1) sm += __shfl_xor(sm, d);             \
            float inv = 1.f / sm;                                                 \
            A0[_j] = e0 * inv;                                                    \
            A1[_j] = e1 * inv;                                                    \
            A2[_j] = v2m ? e2 * inv : 0.f;                                        \
        }                                                                         \
    } while (0)

        SOFTMAX_RS(a0_0, a0_1, a0_2);
        SOFTMAX_RS(a1_0, a1_1, a1_2);
    }

    // ================= pass 2: encodings, weighted sum =================
    const bf16x8* bo = wf + (size_t)112 * 128;
    const bf16x8 Boh0 = bo[lane],       Bol0 = bo[64 + lane];
    const bf16x8 Boh1 = bo[128 + lane], Bol1 = bo[192 + lane];

    f32x4 at0_0 = zf, at0_1 = zf, at1_0 = zf, at1_1 = zf;
    const int grp = lane & 48;     // 16*s: owner-group base for weight shuffles

#define SELF_ENC(OROW, WREG, AT0, AT1)                                            \
    do {                                                                          \
        f32x4 e0 = zf, e1 = zf;                                                   \
        {                                                                         \
            float4 p = ld4((OROW) + s * 8), q = ld4((OROW) + s * 8 + 4);          \
            float av[8] = {p.x, p.y, p.z, p.w, q.x, q.y, q.z, q.w};               \
            bf16x8 ah, al; split8(av, ah, al);                                    \
            const bf16x8* bu = wf + (size_t)108 * 128;                            \
            e0 = mm3(ah, al, bu[lane], bu[64 + lane], e0);                        \
            e1 = mm3(ah, al, bu[128 + lane], bu[192 + lane], e1);                 \
        }                                                                         \
        {                                                                         \
            float av[8] = {0, 0, 0, 0, 0, 0, 0, 0};                               \
            if (s == 0) {                                                         \
                float4 p = ld4((OROW) + 32);                                      \
                av[0] = p.x; av[1] = p.y; av[2] = p.z; av[3] = p.w;               \
                av[4] = (OROW)[36];                                               \
            }                                                                     \
            bf16x8 ah, al; split8(av, ah, al);                                    \
            const bf16x8* bu = wf + (size_t)110 * 128;                            \
            e0 = mm3(ah, al, bu[lane], bu[64 + lane], e0);                        \
            e1 = mm3(ah, al, bu[128 + lane], bu[192 + lane], e1);                 \
        }                                                                         \
        _Pragma("unroll")                                                         \
        for (int _j = 0; _j < 4; ++_j) {                                          \
            float w0 = __shfl(WREG[_j], grp);    /* att col 0 = self */           \
            AT0[_j] = w0 * e0[_j];                                                \
            AT1[_j] = w0 * e1[_j];                                                \
        }                                                                         \
    } while (0)

    SELF_ENC(orow0, a0_0, at0_0, at0_1);
    SELF_ENC(orow1, a1_0, at1_0, at1_1);

    // ---- other agents: coalesced [32][32]f windows, wave-private tri-buffer ----
    asm volatile("s_waitcnt vmcnt(0)" ::: "memory");   // clean slate for ledger

    const size_t pB0 = (size_t)(rowbase + (lane >> 3)) * OBS + 36 + 4 * ((lane & 7) ^ (lane >> 3));
    const size_t pB1 = pB0 + (size_t)8 * OBS;
    const size_t pB2 = pB0 + (size_t)16 * OBS;
    const size_t pB3 = pB0 + (size_t)24 * OBS;

#define STAGE_W(K, N)                                                             \
    do {                                                                          \
        char* _d = AW + (K) * 4096;                                               \
        glds16(obs + pB0 + 28 * (N), _d);                                         \
        glds16(obs + pB1 + 28 * (N), _d + 1024);                                  \
        glds16(obs + pB2 + 28 * (N), _d + 2048);                                  \
        glds16(obs + pB3 + 28 * (N), _d + 3072);                                  \
    } while (0)

    // FIXED map: weight for agent N is att col 1+N ->
    //   owner lane = grp | ((N+1)&15), register class = (N+1)>>4.
#define PROC_W(N, U00, U01, U10, U11, W0REG, W1REG)                               \
    do {                                                                          \
        bf16x8 _h0, _h1;                                                          \
        _h0[0] = (__bf16)(U00).x; _h0[1] = (__bf16)(U00).y;                       \
        _h0[2] = (__bf16)(U00).z; _h0[3] = (__bf16)(U00).w;                       \
        _h0[4] = (__bf16)(U01).x; _h0[5] = (__bf16)(U01).y;                       \
        _h0[6] = (__bf16)(U01).z; _h0[7] = (__bf16)(U01).w;                       \
        _h1[0] = (__bf16)(U10).x; _h1[1] = (__bf16)(U10).y;                       \
        _h1[2] = (__bf16)(U10).z; _h1[3] = (__bf16)(U10).w;                       \
        _h1[4] = (__bf16)(U11).x; _h1[5] = (__bf16)(U11).y;                       \
        _h1[6] = (__bf16)(U11).z; _h1[7] = (__bf16)(U11).w;                       \
        __builtin_amdgcn_s_setprio(1);                                            \
        f32x4 _e00 = MFMA(_h0, Boh0, zf); _e00 = MFMA(_h0, Bol0, _e00);           \
        f32x4 _e01 = MFMA(_h0, Boh1, zf); _e01 = MFMA(_h0, Bol1, _e01);           \
        f32x4 _e10 = MFMA(_h1, Boh0, zf); _e10 = MFMA(_h1, Bol0, _e10);           \
        f32x4 _e11 = MFMA(_h1, Boh1, zf); _e11 = MFMA(_h1, Bol1, _e11);           \
        __builtin_amdgcn_s_setprio(0);                                            \
        const int _src = grp | (((N) + 1) & 15);                                  \
        _Pragma("unroll")                                                         \
        for (int _j = 0; _j < 4; ++_j) {                                          \
            float _w0 = __shfl(W0REG[_j], _src);                                  \
            float _w1 = __shfl(W1REG[_j], _src);                                  \
            at0_0[_j] += _w0 * fmaxf(_e00[_j], 0.f);                              \
            at0_1[_j] += _w0 * fmaxf(_e01[_j], 0.f);                              \
            at1_0[_j] += _w1 * fmaxf(_e10[_j], 0.f);                              \
            at1_1[_j] += _w1 * fmaxf(_e11[_j], 0.f);                              \
        }                                                                         \
    } while (0)

#define P2_ITER(W, VM, DOSTAGE, W0REG, W1REG)                                     \
    do {                                                                          \
        asm volatile("s_waitcnt vmcnt(" #VM ")" ::: "memory");                    \
        __builtin_amdgcn_sched_barrier(0);                                        \
        const char* _ab = AW + ((W) % 3) * 4096;                                  \
        float4 u00 = *(const float4*)(_ab + rdA0);                                \
        float4 u01 = *(const float4*)(_ab + rdA1);                                \
        float4 u10 = *(const float4*)(_ab + 2048 + rdA0);                         \
        float4 u11 = *(const float4*)(_ab + 2048 + rdA1);                         \
        asm volatile("s_waitcnt lgkmcnt(0)" ::: "memory");                        \
        __builtin_amdgcn_sched_barrier(0);                                        \
        if (DOSTAGE) STAGE_W((W) % 3, (W) + 3);                                   \
        PROC_W(W, u00, u01, u10, u11, W0REG, W1REG);                              \
    } while (0)

    STAGE_W(0, 0); STAGE_W(1, 1); STAGE_W(2, 2);

    // class grouping by att col 1+w: w 0..14 -> class 0, 15..30 -> 1, 31..38 -> 2
    for (int w = 0; w < 15; ++w)
        P2_ITER(w, 8, true, a0_0, a1_0);
    for (int w = 15; w < 31; ++w)
        P2_ITER(w, 8, true, a0_1, a1_1);
    for (int w = 31; w < 35; ++w)
        P2_ITER(w, 8, true, a0_2, a1_2);
    P2_ITER(35, 8, false, a0_2, a1_2);
    P2_ITER(36, 4, false, a0_2, a1_2);
    P2_ITER(37, 0, false, a0_2, a1_2);

    {   // agent 38 via VGPR loads (avoids OOB read past obs end)
#define A38(OROW, U0, U1)                                                         \
        float4 U0, U1;                                                            \
        do {                                                                      \
            const float* _op = (OROW) + 1100;                                     \
            if (s < 3) {                                                          \
                U0 = ld4(_op + s * 8);                                            \
                U1 = ld4(_op + s * 8 + 4);                                        \
            } else {                                                              \
                U0 = ld4(_op + 24);                                               \
                U1.x = _op[28]; U1.y = 0.f; U1.z = 0.f; U1.w = 0.f;               \
            }                                                                     \
        } while (0)
        A38(orow0, u00, u01);
        A38(orow1, u10, u11);
        PROC_W(38, u00, u01, u10, u11, a0_2, a1_2);
    }

    // ============ head: 3 dense layers per rowset, wave-private LDS ============
    __bf16* hiw = (__bf16*)AW;
    __bf16* low = hiw + 640;

#define HEAD_AND_OUT(AT0, AT1, ROWB)                                              \
    do {                                                                          \
        f32x4 x0 = AT0, x1 = AT1;                                                 \
        _Pragma("unroll")                                                         \
        for (int L = 0; L < 3; ++L) {                                             \
            const int unit = 114 + L * 2;                                         \
            const float* bias = (L == 0) ? b_ao : (L == 1) ? b_emb : b_out;       \
            const int N = (L == 2) ? 21 : 32;                                     \
            _Pragma("unroll")                                                     \
            for (int _j = 0; _j < 4; ++_j) {                                      \
                const int row = s * 4 + _j;                                       \
                __bf16 h0 = (__bf16)x0[_j];                                       \
                hiw[row * 40 + cq] = h0;                                          \
                low[row * 40 + cq] = (__bf16)(x0[_j] - (float)h0);                \
                __bf16 h1 = (__bf16)x1[_j];                                       \
                hiw[row * 40 + 16 + cq] = h1;                                     \
                low[row * 40 + 16 + cq] = (__bf16)(x1[_j] - (float)h1);           \
            }                                                                     \
            bf16x8 ah = *(const bf16x8*)&hiw[cq * 40 + s * 8];                    \
            bf16x8 al = *(const bf16x8*)&low[cq * 40 + s * 8];                    \
            const bf16x8* bu = wf + (size_t)unit * 128;                           \
            f32x4 y0 = mm3(ah, al, bu[lane], bu[64 + lane], zf);                  \
            f32x4 y1 = mm3(ah, al, bu[128 + lane], bu[192 + lane], zf);           \
            const float bc0 = bias[cq];                                           \
            const float bc1 = (16 + cq < N) ? bias[16 + cq] : 0.f;                \
            _Pragma("unroll")                                                     \
            for (int _j = 0; _j < 4; ++_j) {                                      \
                y0[_j] += bc0;                                                    \
                y1[_j] += bc1;                                                    \
                if (L < 2) { y0[_j] = fmaxf(y0[_j], 0.f); y1[_j] = fmaxf(y1[_j], 0.f); } \
            }                                                                     \
            x0 = y0; x1 = y1;                                                     \
        }                                                                         \
        _Pragma("unroll")                                                         \
        for (int _j = 0; _j < 4; ++_j) {                                          \
            const int row = (ROWB) + s * 4 + _j;                                  \
            out[(size_t)row * 21 + cq] = x0[_j];                                  \
            if (cq < 5) out[(size_t)row * 21 + 16 + cq] = x1[_j];                 \
        }                                                                         \
    } while (0)

    HEAD_AND_OUT(at0_0, at0_1, rowbase);
    HEAD_AND_OUT(at1_0, at1_1, rowbase + 16);
}

extern "C" void kernel_launch(void* const* d_in, const int* in_sizes, int n_in,
                              void* d_out, int out_size, void* d_ws, size_t ws_size,
                              hipStream_t stream) {
    const float* obs    = (const float*)d_in[0];
    const float* W_al   = (const float*)d_in[1];
    const float* b_al   = (const float*)d_in[2];
    const float* W_self = (const float*)d_in[3];
    const float* W_oth  = (const float*)d_in[5];
    const float* W_ao   = (const float*)d_in[7];
    const float* b_ao   = (const float*)d_in[8];
    const float* W_emb  = (const float*)d_in[9];
    const float* b_emb  = (const float*)d_in[10];
    const float* W_out  = (const float*)d_in[11];
    const float* b_out  = (const float*)d_in[12];
    float* out = (float*)d_out;
    bf16x8* ws = (bf16x8*)d_ws;

    prep_weights<<<120, 64, 0, stream>>>(W_al, W_self, W_oth, W_ao, W_emb, W_out, ws);

    const int B = in_sizes[0] / OBS;        // 65536
    qnet_fwd<<<B / 128, 256, 0, stream>>>(obs, b_al, b_ao, b_emb, b_out,
                                          (const bf16x8*)ws, out);
}

// Round 13
// 108.340 us; speedup vs baseline: 1.3802x; 1.1169x over previous
//
#include <hip/hip_runtime.h>

// QNet forward, MI355X — R13: R9 structure, B-hi-only staging (half B bytes).
// B=65536 rows, obs=1129 (37 self + 39*28 others).
// 256 thr (4 waves), 64 rows/block (16/wave), grid 1024, 2 blocks/CU (~60KB LDS).
//
// R12 post-mortem: per-CU vmem streaming is saturated (R9 = 7.5 TB/s effective
// ~ m13 ceiling; warm==cold because L1-miss path cost is residency-blind).
// Lever = bytes. R13 = R9 exactly, but pass-1 W_al staged HI-ONLY:
//   logits 2-term: ah*bh + al*bh  (A full precision, B bf16, ~4e-3 logit err)
// B bytes/chunk 6KB->3KB; 3 glds/chunk block-wide (1/wave, wave3 dup t=0);
// ledger: 3 ops/chunk/wave, steady vmcnt(6), tail 6/4/1/0.
//
// Staging (R9-verified): coalesced glds16, source-swizzled A tiles
//   LDS[r][p] = global unit p^(r&7); read pos g^(r&7).
// Fragment maps (gfx950 16x16x32 bf16): A/B: row|col = lane&15, k = 8*(lane>>4)+i
//   C/D: col = lane&15, row = 4*(lane>>4) + reg
// Split-bf16: logits 2-term(B-hi), self/head 3-term, others 2-term(A-hi).
//
// d_ws: 120 units of 128 bf16x8 (64 hi + 64 lo), 2KB each (layout unchanged;
// pass-1 just reads only the hi halves).
//   W_al: c*3+t | W_self: 108+c*2+t | W_oth'(K=32, leading zero row): 112+t
//   W_ao: 114+t | W_emb: 116+t | W_out: 118+t

typedef __bf16 bf16x8 __attribute__((ext_vector_type(8)));
typedef float  f32x4  __attribute__((ext_vector_type(4)));

constexpr int OBS = 1129;

#define MFMA(a, b, c) __builtin_amdgcn_mfma_f32_16x16x32_bf16((a), (b), (c), 0, 0, 0)

__device__ __forceinline__ float4 ld4(const float* p) {
    float4 v;
    __builtin_memcpy(&v, p, 16);
    return v;
}

__device__ __forceinline__ void split8(const float* a, bf16x8& h, bf16x8& l) {
#pragma unroll
    for (int i = 0; i < 8; ++i) {
        __bf16 hb = (__bf16)a[i];
        h[i] = hb;
        l[i] = (__bf16)(a[i] - (float)hb);
    }
}

__device__ __forceinline__ f32x4 mm3(bf16x8 ah, bf16x8 al, bf16x8 bh, bf16x8 bl, f32x4 c) {
    c = MFMA(ah, bh, c);
    c = MFMA(ah, bl, c);
    c = MFMA(al, bh, c);
    return c;
}

__device__ __forceinline__ void glds16(const void* g, void* l) {
    __builtin_amdgcn_global_load_lds((const __attribute__((address_space(1))) void*)g,
                                     (__attribute__((address_space(3))) void*)l, 16, 0, 0);
}

// ---------------- prep: split weights into fragment order ----------------
__global__ void prep_weights(const float* __restrict__ W_al,
                             const float* __restrict__ W_self,
                             const float* __restrict__ W_oth,
                             const float* __restrict__ W_ao,
                             const float* __restrict__ W_emb,
                             const float* __restrict__ W_out,
                             bf16x8* __restrict__ ws)
{
    const int u = blockIdx.x;     // 120 units
    const int l = threadIdx.x;    // 64 lanes
    const int s = l >> 4, col = l & 15;
    const float* W; int K, N, ld, c, t, shift = 0;
    if (u < 108)      { c = u / 3;         t = u % 3;         W = W_al;   K = 1129; N = 40; ld = 40; }
    else if (u < 112) { c = (u - 108) / 2; t = (u - 108) & 1; W = W_self; K = 37;   N = 32; ld = 32; }
    else if (u < 114) { c = 0;             t = u - 112;       W = W_oth;  K = 28;   N = 32; ld = 32; shift = 1; }
    else if (u < 116) { c = 0;             t = u - 114;       W = W_ao;   K = 32;   N = 32; ld = 32; }
    else if (u < 118) { c = 0;             t = u - 116;       W = W_emb;  K = 32;   N = 32; ld = 32; }
    else              { c = 0;             t = u - 118;       W = W_out;  K = 32;   N = 21; ld = 21; }
    const int j = t * 16 + col;
    bf16x8 h, lo;
#pragma unroll
    for (int i = 0; i < 8; ++i) {
        int k = c * 32 + s * 8 + i;
        int kk = k - shift;
        float w = (kk >= 0 && kk < K && j < N) ? W[kk * ld + j] : 0.f;
        __bf16 hb = (__bf16)w;
        h[i]  = hb;
        lo[i] = (__bf16)(w - (float)hb);
    }
    ws[u * 128 + l]      = h;
    ws[u * 128 + 64 + l] = lo;
}

// ---------------- main kernel: 256 threads (4 waves), 64 rows ----------------
__global__ __launch_bounds__(256, 2)
void qnet_fwd(const float* __restrict__ obs,
              const float* __restrict__ b_al,
              const float* __restrict__ b_ao,
              const float* __restrict__ b_emb,
              const float* __restrict__ b_out,
              const bf16x8* __restrict__ wf,
              float* __restrict__ out)
{
    // arena layout:
    //  pass1: A quad-buf [0,32768): buf k at k*8192, wave slice +wv*2048 (2KB tile)
    //         B(hi) quad-buf [32768,45056): buf k at 32768+k*3072
    //  pass2: wave-private tri-buf at wv*12288 (3 x 4KB windows); head reuses it
    __shared__ __align__(16) char arena[49152];
    __shared__ float sW[4 * 656];               // per-wave att weights [16][41]

    const int t    = threadIdx.x;
    const int lane = t & 63;
    const int wv   = t >> 6;
    const int s    = lane >> 4;
    const int cq   = lane & 15;
    const int rowbase = blockIdx.x * 64 + wv * 16;
    const float* __restrict__ orow = obs + (size_t)(rowbase + cq) * OBS;
    const char* __restrict__ wfb = (const char*)wf;
    float* __restrict__ sWw = sW + wv * 656;

    const f32x4 zf = {0.f, 0.f, 0.f, 0.f};

    // ---- pass-1 A staging bases (coalesced, source-swizzled) ----
    const size_t aB0 = (size_t)(rowbase + (lane >> 3)) * OBS + 4 * ((lane & 7) ^ (lane >> 3));
    const size_t aB1 = aB0 + (size_t)8 * OBS;
    const unsigned rdA0 = (unsigned)(cq * 128 + (((2 * s)     ^ (cq & 7)) << 4));
    const unsigned rdA1 = (unsigned)(cq * 128 + (((2 * s + 1) ^ (cq & 7)) << 4));

    char* const Abase = arena + wv * 2048;      // + k*8192
    char* const Bbase = arena + 32768;          // + k*3072 (hi-only, 3KB/chunk)
    const int bt = wv % 3;                      // B piece this wave stages (w3 dups 0)

#define STAGE_A(K, C)                                                             \
    do {                                                                          \
        char* _d = Abase + (K) * 8192;                                            \
        glds16(obs + aB0 + (C) * 32, _d);                                         \
        glds16(obs + aB1 + (C) * 32, _d + 1024);                                  \
    } while (0)
    // hi-only: unit (3C+bt) hi half = wfb + C*6144 + bt*2048
#define STAGE_BH(K, C)                                                            \
    do {                                                                          \
        glds16(wfb + (size_t)(C) * 6144 + (size_t)bt * 2048 + lane * 16,          \
               Bbase + (K) * 3072 + bt * 1024);                                   \
    } while (0)

    // ================= pass 1: logits = obs @ W_al =================
    f32x4 acc0 = zf, acc1 = zf, acc2 = zf;

#define P1_MATH(FA0, FA1, BP)                                                     \
    do {                                                                          \
        float _av[8] = {(FA0).x, (FA0).y, (FA0).z, (FA0).w,                       \
                        (FA1).x, (FA1).y, (FA1).z, (FA1).w};                      \
        bf16x8 _ah, _al; split8(_av, _ah, _al);                                   \
        const char* _bp = (const char*)(BP);                                      \
        bf16x8 b0 = *(const bf16x8*)(_bp + lane * 16);                            \
        bf16x8 b1 = *(const bf16x8*)(_bp + 1024 + lane * 16);                     \
        bf16x8 b2 = *(const bf16x8*)(_bp + 2048 + lane * 16);                     \
        __builtin_amdgcn_s_setprio(1);                                            \
        acc0 = MFMA(_ah, b0, acc0); acc0 = MFMA(_al, b0, acc0);                   \
        acc1 = MFMA(_ah, b1, acc1); acc1 = MFMA(_al, b1, acc1);                   \
        acc2 = MFMA(_ah, b2, acc2); acc2 = MFMA(_al, b2, acc2);                   \
        __builtin_amdgcn_s_setprio(0);                                            \
    } while (0)

    // prologue: stage chunks 0,1,2 (9 vmem ops/wave: 3/chunk)
    STAGE_A(0, 0); STAGE_BH(0, 0);
    STAGE_A(1, 1); STAGE_BH(1, 1);
    STAGE_A(2, 2); STAGE_BH(2, 2);

    // steady: compute c, stage c+3 (c+3 <= 34). 3 ops/chunk -> vmcnt(6)=2 chunks.
    for (int c = 0; c < 32; ++c) {
        const int kc = c & 3, kn = (c + 3) & 3;
        asm volatile("s_waitcnt vmcnt(6)" ::: "memory");   // chunk c complete
        __builtin_amdgcn_s_barrier();
        __builtin_amdgcn_sched_barrier(0);
        const char* ab = Abase + kc * 8192;
        float4 fa0 = *(const float4*)(ab + rdA0);
        float4 fa1 = *(const float4*)(ab + rdA1);
        asm volatile("s_waitcnt lgkmcnt(0)" ::: "memory");
        __builtin_amdgcn_sched_barrier(0);
        STAGE_A(kn, c + 3);
        STAGE_BH(kn, c + 3);
        P1_MATH(fa0, fa1, Bbase + kc * 3072);
    }
    {   // c = 32: also stage B(35) into slot 3 (chunk 31's slot, readers done)
        asm volatile("s_waitcnt vmcnt(6)" ::: "memory");
        __builtin_amdgcn_s_barrier();
        __builtin_amdgcn_sched_barrier(0);
        const char* ab = Abase + 0 * 8192;
        float4 fa0 = *(const float4*)(ab + rdA0);
        float4 fa1 = *(const float4*)(ab + rdA1);
        asm volatile("s_waitcnt lgkmcnt(0)" ::: "memory");
        __builtin_amdgcn_sched_barrier(0);
        STAGE_BH(3, 35);
        P1_MATH(fa0, fa1, Bbase + 0 * 3072);
    }
    {   // c = 33  (outstanding: 34(3), B35(1) = 4 after wait)
        asm volatile("s_waitcnt vmcnt(4)" ::: "memory");
        __builtin_amdgcn_s_barrier();
        __builtin_amdgcn_sched_barrier(0);
        const char* ab = Abase + 1 * 8192;
        float4 fa0 = *(const float4*)(ab + rdA0);
        float4 fa1 = *(const float4*)(ab + rdA1);
        P1_MATH(fa0, fa1, Bbase + 1 * 3072);
    }
    {   // c = 34  (outstanding: B35(1) after wait)
        asm volatile("s_waitcnt vmcnt(1)" ::: "memory");
        __builtin_amdgcn_s_barrier();
        __builtin_amdgcn_sched_barrier(0);
        const char* ab = Abase + 2 * 8192;
        float4 fa0 = *(const float4*)(ab + rdA0);
        float4 fa1 = *(const float4*)(ab + rdA1);
        P1_MATH(fa0, fa1, Bbase + 2 * 3072);
    }
    {   // c = 35: masked A tail (k=1120..1128) via VGPR loads; B35 in slot 3
        asm volatile("s_waitcnt vmcnt(0)" ::: "memory");
        __builtin_amdgcn_s_barrier();
        __builtin_amdgcn_sched_barrier(0);
        float av[8] = {0, 0, 0, 0, 0, 0, 0, 0};
        if (s == 0) {
            float4 p = ld4(orow + 1120), q = ld4(orow + 1124);
            av[0] = p.x; av[1] = p.y; av[2] = p.z; av[3] = p.w;
            av[4] = q.x; av[5] = q.y; av[6] = q.z; av[7] = q.w;
        } else if (s == 1) {
            av[0] = orow[1128];
        }
        float4 fa0 = {av[0], av[1], av[2], av[3]};
        float4 fa1 = {av[4], av[5], av[6], av[7]};
        P1_MATH(fa0, fa1, Bbase + 3 * 3072);
    }
    __syncthreads();   // arena handoff: pass-2 regions overlap pass-1 bufs

    // ===== softmax over 40 cols (intra-wave; C rows: row = 4s+j) =====
    {
        const float bal0 = b_al[cq];
        const float bal1 = b_al[16 + cq];
        const bool  v2m  = (cq < 8);
        const float bal2 = v2m ? b_al[32 + cq] : 0.f;
#pragma unroll
        for (int j = 0; j < 4; ++j) {
            float v0 = acc0[j] + bal0, v1 = acc1[j] + bal1, vv = acc2[j] + bal2;
            float m = fmaxf(fmaxf(v0, v1), v2m ? vv : -3.4e38f);
#pragma unroll
            for (int d = 1; d < 16; d <<= 1) m = fmaxf(m, __shfl_xor(m, d));
            float e0 = __expf(v0 - m), e1 = __expf(v1 - m);
            float e2 = v2m ? __expf(vv - m) : 0.f;
            float sm = e0 + e1 + e2;
#pragma unroll
            for (int d = 1; d < 16; d <<= 1) sm += __shfl_xor(sm, d);
            float inv = 1.f / sm;
            const int row = s * 4 + j;
            sWw[row * 41 + cq]      = e0 * inv;
            sWw[row * 41 + 16 + cq] = e1 * inv;
            if (v2m) sWw[row * 41 + 32 + cq] = e2 * inv;
        }
    }
    // no barrier: sWw wave-private

    // ================= pass 2: encodings, weighted sum =================
    const bf16x8* bo = wf + (size_t)112 * 128;
    const bf16x8 Boh0 = bo[lane],       Bol0 = bo[64 + lane];
    const bf16x8 Boh1 = bo[128 + lane], Bol1 = bo[192 + lane];

    f32x4 at0 = zf, at1 = zf;
    {   // self encoding (no relu), 3-term, weight att_w[row][0]
        f32x4 e0 = zf, e1 = zf;
        {
            float4 p = ld4(orow + s * 8), q = ld4(orow + s * 8 + 4);
            float av[8] = {p.x, p.y, p.z, p.w, q.x, q.y, q.z, q.w};
            bf16x8 ah, al; split8(av, ah, al);
            const bf16x8* bu = wf + (size_t)108 * 128;
            e0 = mm3(ah, al, bu[lane],       bu[64 + lane],  e0);
            e1 = mm3(ah, al, bu[128 + lane], bu[192 + lane], e1);
        }
        {
            float av[8] = {0, 0, 0, 0, 0, 0, 0, 0};
            if (s == 0) {
                float4 p = ld4(orow + 32);
                av[0] = p.x; av[1] = p.y; av[2] = p.z; av[3] = p.w;
                av[4] = orow[36];
            }
            bf16x8 ah, al; split8(av, ah, al);
            const bf16x8* bu = wf + (size_t)110 * 128;
            e0 = mm3(ah, al, bu[lane],       bu[64 + lane],  e0);
            e1 = mm3(ah, al, bu[128 + lane], bu[192 + lane], e1);
        }
#pragma unroll
        for (int j = 0; j < 4; ++j) {
            float w0 = sWw[(s * 4 + j) * 41];
            at0[j] = w0 * e0[j];
            at1[j] = w0 * e1[j];
        }
    }

    // ---- other agents 0..37 via coalesced wave-private tri-buffer windows ----
    asm volatile("s_waitcnt vmcnt(0)" ::: "memory");   // clean slate for counting

    const unsigned uE = (unsigned)((lane & 15) ^ (lane >> 4));
    const unsigned uO = (unsigned)((lane & 15) ^ (4 + (lane >> 4)));
    const size_t pE = (size_t)(rowbase +     (lane >> 4)) * OBS + 36 + 4 * uE;
    const size_t pO = (size_t)(rowbase + 4 + (lane >> 4)) * OBS + 36 + 4 * uO;
    const size_t p8 = (size_t)8 * OBS;

    char* const Pbase = arena + wv * 12288;   // 3 x 4KB wave-private

#define STAGE_P(K, W)                                                             \
    do {                                                                          \
        char* _d = Pbase + (K) * 4096;                                            \
        glds16(obs + pE + 56 * (W),      _d);                                     \
        glds16(obs + pO + 56 * (W),      _d + 1024);                              \
        glds16(obs + pE + p8 + 56 * (W), _d + 2048);                              \
        glds16(obs + pO + p8 + 56 * (W), _d + 3072);                              \
    } while (0)

    const unsigned rdP00 = rdA0;   // reuse: cq*128+... no — window row stride 256B
    (void)rdP00;
    const unsigned rdQ00 = (unsigned)(cq * 256 + (((2 * s)     ^ (cq & 7)) << 4));
    const unsigned rdQ01 = (unsigned)(cq * 256 + (((2 * s + 1) ^ (cq & 7)) << 4));
    const unsigned rdQ10 = (unsigned)(cq * 256 + (((7 + 2 * s) ^ (cq & 7)) << 4));
    const unsigned rdQ11 = (unsigned)(cq * 256 + (((8 + 2 * s) ^ (cq & 7)) << 4));

#define PROC2(N, U0, U1)                                                          \
    do {                                                                          \
        bf16x8 _ah;                                                               \
        _ah[0] = (__bf16)(U0).x; _ah[1] = (__bf16)(U0).y;                         \
        _ah[2] = (__bf16)(U0).z; _ah[3] = (__bf16)(U0).w;                         \
        _ah[4] = (__bf16)(U1).x; _ah[5] = (__bf16)(U1).y;                         \
        _ah[6] = (__bf16)(U1).z; _ah[7] = (__bf16)(U1).w;                         \
        f32x4 _e0 = MFMA(_ah, Boh0, zf); _e0 = MFMA(_ah, Bol0, _e0);              \
        f32x4 _e1 = MFMA(_ah, Boh1, zf); _e1 = MFMA(_ah, Bol1, _e1);              \
        _Pragma("unroll")                                                         \
        for (int _j = 0; _j < 4; ++_j) {                                          \
            float _wn = sWw[(s * 4 + _j) * 41 + 1 + (N)];                         \
            at0[_j] += _wn * fmaxf(_e0[_j], 0.f);                                 \
            at1[_j] += _wn * fmaxf(_e1[_j], 0.f);                                 \
        }                                                                         \
    } while (0)

#define P2_READS(K)                                                               \
    const char* _q = Pbase + (K) * 4096;                                          \
    float4 u00 = *(const float4*)(_q + rdQ00);                                    \
    float4 u01 = *(const float4*)(_q + rdQ01);                                    \
    float4 u10 = *(const float4*)(_q + rdQ10);                                    \
    float4 u11 = *(const float4*)(_q + rdQ11)

    STAGE_P(0, 0);
    STAGE_P(1, 1);
    STAGE_P(2, 2);

    for (int w = 0; w < 16; ++w) {
        const int kc = w % 3, kn = (w + 3) % 3;
        asm volatile("s_waitcnt vmcnt(8)" ::: "memory");   // window w complete
        __builtin_amdgcn_sched_barrier(0);
        P2_READS(kc);
        asm volatile("s_waitcnt lgkmcnt(0)" ::: "memory");
        __builtin_amdgcn_sched_barrier(0);
        STAGE_P(kn, w + 3);                   // overwrites just-read buffer
        __builtin_amdgcn_s_setprio(1);
        PROC2(2 * w,     u00, u01);
        PROC2(2 * w + 1, u10, u11);
        __builtin_amdgcn_s_setprio(0);
    }
    {   // w = 16
        asm volatile("s_waitcnt vmcnt(8)" ::: "memory");
        __builtin_amdgcn_sched_barrier(0);
        P2_READS(1);
        PROC2(32, u00, u01);
        PROC2(33, u10, u11);
    }
    {   // w = 17
        asm volatile("s_waitcnt vmcnt(4)" ::: "memory");
        __builtin_amdgcn_sched_barrier(0);
        P2_READS(2);
        PROC2(34, u00, u01);
        PROC2(35, u10, u11);
    }
    {   // w = 18
        asm volatile("s_waitcnt vmcnt(0)" ::: "memory");
        __builtin_amdgcn_sched_barrier(0);
        P2_READS(0);
        PROC2(36, u00, u01);
        PROC2(37, u10, u11);
    }
    {   // agent 38 via VGPR loads (virtual k=0 pad row in W_oth')
        const float* op = orow + 1100;        // col 36 + 28*38
        float av[8];
        if (s < 3) {
            float4 p = ld4(op + s * 8), q = ld4(op + s * 8 + 4);
            av[0] = p.x; av[1] = p.y; av[2] = p.z; av[3] = p.w;
            av[4] = q.x; av[5] = q.y; av[6] = q.z; av[7] = q.w;
        } else {
            float4 p = ld4(op + 24);
            av[0] = p.x; av[1] = p.y; av[2] = p.z; av[3] = p.w;
            av[4] = op[28];
            av[5] = 0.f; av[6] = 0.f; av[7] = 0.f;
        }
        float4 u0 = {av[0], av[1], av[2], av[3]};
        float4 u1 = {av[4], av[5], av[6], av[7]};
        PROC2(38, u0, u1);
    }

    // ============ head: 3 dense layers, wave-private LDS (Pbase reuse) ============
    __bf16* hiw = (__bf16*)Pbase;
    __bf16* low = hiw + 640;
    f32x4 x0 = at0, x1 = at1;
#pragma unroll
    for (int L = 0; L < 3; ++L) {
        const int unit = 114 + L * 2;
        const float* bias = (L == 0) ? b_ao : (L == 1) ? b_emb : b_out;
        const int N = (L == 2) ? 21 : 32;
#pragma unroll
        for (int j = 0; j < 4; ++j) {
            const int row = s * 4 + j;
            __bf16 h0 = (__bf16)x0[j];
            hiw[row * 40 + cq] = h0;
            low[row * 40 + cq] = (__bf16)(x0[j] - (float)h0);
            __bf16 h1 = (__bf16)x1[j];
            hiw[row * 40 + 16 + cq] = h1;
            low[row * 40 + 16 + cq] = (__bf16)(x1[j] - (float)h1);
        }
        bf16x8 ah = *(const bf16x8*)&hiw[cq * 40 + s * 8];
        bf16x8 al = *(const bf16x8*)&low[cq * 40 + s * 8];
        const bf16x8* bu = wf + (size_t)unit * 128;
        f32x4 y0 = mm3(ah, al, bu[lane],       bu[64 + lane],  zf);
        f32x4 y1 = mm3(ah, al, bu[128 + lane], bu[192 + lane], zf);
        const float bc0 = bias[cq];
        const float bc1 = (16 + cq < N) ? bias[16 + cq] : 0.f;
#pragma unroll
        for (int j = 0; j < 4; ++j) {
            y0[j] += bc0;
            y1[j] += bc1;
            if (L < 2) { y0[j] = fmaxf(y0[j], 0.f); y1[j] = fmaxf(y1[j], 0.f); }
        }
        x0 = y0; x1 = y1;
    }

#pragma unroll
    for (int j = 0; j < 4; ++j) {
        const int row = rowbase + s * 4 + j;
        out[(size_t)row * 21 + cq] = x0[j];
        if (cq < 5) out[(size_t)row * 21 + 16 + cq] = x1[j];
    }
}

extern "C" void kernel_launch(void* const* d_in, const int* in_sizes, int n_in,
                              void* d_out, int out_size, void* d_ws, size_t ws_size,
                              hipStream_t stream) {
    const float* obs    = (const float*)d_in[0];
    const float* W_al   = (const float*)d_in[1];
    const float* b_al   = (const float*)d_in[2];
    const float* W_self = (const float*)d_in[3];
    const float* W_oth  = (const float*)d_in[5];
    const float* W_ao   = (const float*)d_in[7];
    const float* b_ao   = (const float*)d_in[8];
    const float* W_emb  = (const float*)d_in[9];
    const float* b_emb  = (const float*)d_in[10];
    const float* W_out  = (const float*)d_in[11];
    const float* b_out  = (const float*)d_in[12];
    float* out = (float*)d_out;
    bf16x8* ws = (bf16x8*)d_ws;

    prep_weights<<<120, 64, 0, stream>>>(W_al, W_self, W_oth, W_ao, W_emb, W_out, ws);

    const int B = in_sizes[0] / OBS;        // 65536
    qnet_fwd<<<B / 64, 256, 0, stream>>>(obs, b_al, b_ao, b_emb, b_out,
                                         (const bf16x8*)ws, out);
}